// Round 5
// baseline (261.045 us; speedup 1.0000x reference)
//
#include <hip/hip_runtime.h>
#include <hip/hip_bf16.h>

// Problem constants (B,T,C,H from reference)
#define BATCH 8
#define SEQ   2048
#define EMB   1024
#define HD    128

typedef __attribute__((ext_vector_type(8))) short bf16x8;  // MFMA A/B frag (4 VGPR)
typedef __attribute__((ext_vector_type(4))) float f32x4;   // MFMA C/D frag

__device__ __forceinline__ short f2bf(float f) {           // RNE
    union { float f; unsigned u; } v; v.f = f;
    unsigned r = v.u + 0x7fffu + ((v.u >> 16) & 1u);
    return (short)(r >> 16);
}

// ---------------------------------------------------------------------------
// prep_w: Wk,Wv fp32 -> bf16 once, swizzled to MFMA-B-fragment order:
//   Wp[((k>>3)*256 + n2)*8 + (k&7)] = W[n2][k],  n2<128 = K row, else V row.
// ---------------------------------------------------------------------------
__global__ void prep_w(const float* __restrict__ Wk, const float* __restrict__ Wv,
                       short* __restrict__ Wp) {
    int g  = blockIdx.x * 256 + threadIdx.x;
    int n2 = g >> 7;
    int s  = g & 127;
    const float* src = (n2 < 128) ? (Wk + (size_t)n2 * EMB)
                                  : (Wv + (size_t)(n2 - 128) * EMB);
    src += s * 8;
    float4 f0 = *(const float4*)src;
    float4 f1 = *(const float4*)(src + 4);
    bf16x8 v;
    v[0]=f2bf(f0.x); v[1]=f2bf(f0.y); v[2]=f2bf(f0.z); v[3]=f2bf(f0.w);
    v[4]=f2bf(f1.x); v[5]=f2bf(f1.y); v[6]=f2bf(f1.z); v[7]=f2bf(f1.w);
    *(bf16x8*)&Wp[((size_t)s * 256 + n2) * 8] = v;
}

// ---------------------------------------------------------------------------
// proj_kernel v5: [K|V] = x @ [Wk|Wv]^T.
// launch_bounds(256,2): 256-VGPR budget so all 16 Wp B-frags per chunk can be
// IN FLIGHT simultaneously (v4's (,4) bound forced 64 VGPRs -> serialized
// load->waitcnt(0)->use round-trips at ~350 cyc each; that was the gate).
// x staged through LDS (coalesced, dbuf, 1 barrier/chunk); Wp direct from L2.
// ---------------------------------------------------------------------------
__global__ __launch_bounds__(256, 2)
void proj_kernel(const float* __restrict__ x, const short* __restrict__ Wp,
                 short* __restrict__ Kout,    // [B*T, H] bf16
                 short* __restrict__ VtOut)   // [B, H, T] bf16
{
    __shared__ __align__(16) union {
        short xs[2][32][72];                          // staging (dbuf, +8 pad)
        struct { short k[32][136]; short v[128][40]; } ep;  // epilogue tiles
    } sm;

    const int tid  = threadIdx.x;
    const int wave = tid >> 6;
    const int lane = tid & 63;
    const int quad = lane >> 4;
    const int l16  = lane & 15;
    const int wm   = wave >> 1;      // m-half (16 rows)
    const int wn   = wave & 1;       // 0 = K cols, 1 = V cols
    const int row0 = blockIdx.x * 32;

    const int sr = tid >> 3;
    const int sc = (tid & 7) * 8;
    const float* xsrc = x + (size_t)(row0 + sr) * EMB + sc;
    const short* wpw  = Wp + (size_t)(wn * 128 + l16) * 8;

    f32x4 acc[8];
#pragma unroll
    for (int f = 0; f < 8; ++f) acc[f] = f32x4{0.f, 0.f, 0.f, 0.f};

    {   // stage chunk 0
        float4 a0 = *(const float4*)xsrc;
        float4 a1 = *(const float4*)(xsrc + 4);
        bf16x8 v;
        v[0]=f2bf(a0.x); v[1]=f2bf(a0.y); v[2]=f2bf(a0.z); v[3]=f2bf(a0.w);
        v[4]=f2bf(a1.x); v[5]=f2bf(a1.y); v[6]=f2bf(a1.z); v[7]=f2bf(a1.w);
        *(bf16x8*)&sm.xs[0][sr][sc] = v;
    }
    __syncthreads();

    for (int kc = 0; kc < 16; ++kc) {
        const int cur = kc & 1;
        float4 n0, n1;
        if (kc < 15) {                       // next chunk's HBM loads fly now
            const float* nx = xsrc + (kc + 1) * 64;
            n0 = *(const float4*)nx;
            n1 = *(const float4*)(nx + 4);
        }
        // issue ALL 16 B-frag loads (64 VGPRs in flight), then MFMA burst
        bf16x8 wfr[16];
#pragma unroll
        for (int kk = 0; kk < 2; ++kk) {
            const int sl = kc * 8 + kk * 4 + quad;
#pragma unroll
            for (int f = 0; f < 8; ++f)
                wfr[kk * 8 + f] = *(const bf16x8*)&wpw[((size_t)sl * 256 + f * 16) * 8];
        }
#pragma unroll
        for (int kk = 0; kk < 2; ++kk) {
            bf16x8 af = *(const bf16x8*)&sm.xs[cur][wm * 16 + l16][kk * 32 + quad * 8];
#pragma unroll
            for (int f = 0; f < 8; ++f)
                acc[f] = __builtin_amdgcn_mfma_f32_16x16x32_bf16(af, wfr[kk * 8 + f], acc[f], 0, 0, 0);
        }
        if (kc < 15) {                       // stage next chunk
            bf16x8 v;
            v[0]=f2bf(n0.x); v[1]=f2bf(n0.y); v[2]=f2bf(n0.z); v[3]=f2bf(n0.w);
            v[4]=f2bf(n1.x); v[5]=f2bf(n1.y); v[6]=f2bf(n1.z); v[7]=f2bf(n1.w);
            *(bf16x8*)&sm.xs[cur ^ 1][sr][sc] = v;
        }
        __syncthreads();
    }

    // ---- epilogue: C-layout (row = quad*4+r, col = f*16+l16) -> LDS transpose
    if (wn == 0) {
#pragma unroll
        for (int f = 0; f < 8; ++f)
#pragma unroll
            for (int r = 0; r < 4; ++r)
                sm.ep.k[wm * 16 + quad * 4 + r][f * 16 + l16] = f2bf(acc[f][r]);
    } else {
#pragma unroll
        for (int f = 0; f < 8; ++f)
#pragma unroll
            for (int r = 0; r < 4; ++r)
                sm.ep.v[f * 16 + l16][wm * 16 + quad * 4 + r] = f2bf(acc[f][r]);
    }
    __syncthreads();

    {   // K: 32 rows x 128 h; thread = (row, 16-short segment)
        int row = tid >> 3, seg = tid & 7;
        short* dst = Kout + (size_t)(row0 + row) * HD + seg * 16;
        *(bf16x8*)dst       = *(const bf16x8*)&sm.ep.k[row][seg * 16];
        *(bf16x8*)(dst + 8) = *(const bf16x8*)&sm.ep.k[row][seg * 16 + 8];
    }
    {   // Vt: 128 h x 32 t; thread = (h, 16-short half)
        int h = tid >> 1, half = tid & 1;
        int b = row0 >> 11, t0 = row0 & 2047;
        short* dst = VtOut + ((size_t)(b * HD + h)) * SEQ + t0 + half * 16;
        *(bf16x8*)dst       = *(const bf16x8*)&sm.ep.v[h][half * 16];
        *(bf16x8*)(dst + 8) = *(const bf16x8*)&sm.ep.v[h][half * 16 + 8];
    }
}

// ---------------------------------------------------------------------------
// attn_kernel v5: causal flash attention, q == k (reference bug).
// No online max (scores bounded -> fp32-safe); partials merge by ADDITION.
// launch_bounds(256,2): 256-VGPR budget -> all 16 K-frags then 16 V-frags of
// a j-tile live in registers, loads issue back-to-back and overlap (this was
// the R2-R4 gate: 64-VGPR cap serialized ~32 L2 loads/tile at ~350cyc each).
// Grid 1024 x 256: block = (b = bx&7 XCD swizzle, one 16-row q-tile via
// alternating long/short map); 4 waves split the j-range, no loop barriers.
// ---------------------------------------------------------------------------
#define LOG2E 1.4426950408889634f

__global__ __launch_bounds__(256, 2)
void attn_kernel(const short* __restrict__ Kb,   // [B*T, H] bf16
                 const short* __restrict__ Vt,   // [B, H, T] bf16
                 float* __restrict__ out)        // [B, T, H] fp32
{
    __shared__ __align__(16) short ps[4][1024];   // per-wave swizzled P (16x64)
    __shared__ float obuf[16][132];               // block O accum (+4 pad)
    __shared__ float lbuf[4][16];                 // per-wave row sums

    const int tid  = threadIdx.x;
    const int wave = tid >> 6;
    const int lane = tid & 63;
    const int quad = lane >> 4;
    const int l16  = lane & 15;

    const int b  = blockIdx.x & 7;               // XCD-affinity swizzle
    const int g  = blockIdx.x >> 3;              // 0..127
    const int qt = (g & 1) ? (127 - (g >> 1)) : (g >> 1);  // long/short alternate
    const int n  = (qt >> 2) + 1;                // # of 64-wide j-tiles (causal)
    const int c  = (n + 3) >> 2;                 // j-tiles per wave
    const int jt0 = wave * c;
    const int jt1 = (n < jt0 + c) ? n : (jt0 + c);

    // zero O accumulator
    for (int i = tid; i < 16 * 132; i += 256) ((float*)obuf)[i] = 0.f;

    // Q fragments in registers (Q = K projection)
    const short* qbase = Kb + (size_t)(b * SEQ + qt * 16 + l16) * HD;
    bf16x8 qf[4];
#pragma unroll
    for (int kc = 0; kc < 4; ++kc)
        qf[kc] = *(const bf16x8*)&qbase[kc * 32 + quad * 8];

    f32x4 O[8];
#pragma unroll
    for (int f = 0; f < 8; ++f) O[f] = f32x4{0.f, 0.f, 0.f, 0.f};
    float lp[4] = {0.f, 0.f, 0.f, 0.f};

    const float coef = LOG2E * 0.03125f;   // log2(e)/sqrt(C), sqrt(1024)=32
    short* psw = ps[wave];

    for (int jt = jt0; jt < jt1; ++jt) {
        const int j0 = jt * 64;
        const short* kb = Kb + (size_t)(b * SEQ + j0) * HD;

        // all 16 K B-frags issued together (64 VGPRs in flight)
        bf16x8 kfr[16];
#pragma unroll
        for (int kc = 0; kc < 4; ++kc)
#pragma unroll
            for (int js = 0; js < 4; ++js)
                kfr[kc * 4 + js] = *(const bf16x8*)&kb[(size_t)(js * 16 + l16) * HD + kc * 32 + quad * 8];

        f32x4 S[4];
#pragma unroll
        for (int js = 0; js < 4; ++js) S[js] = f32x4{0.f, 0.f, 0.f, 0.f};
#pragma unroll
        for (int kc = 0; kc < 4; ++kc)
#pragma unroll
            for (int js = 0; js < 4; ++js)
                S[js] = __builtin_amdgcn_mfma_f32_16x16x32_bf16(qf[kc], kfr[kc * 4 + js], S[js], 0, 0, 0);

        // all 16 V B-frags issued now; they fly during exp + P round-trip
        bf16x8 vfr[16];
#pragma unroll
        for (int jc = 0; jc < 2; ++jc)
#pragma unroll
            for (int f = 0; f < 8; ++f)
                vfr[jc * 8 + f] = *(const bf16x8*)&Vt[(size_t)(b * HD + f * 16 + l16) * SEQ + j0 + jc * 32 + quad * 8];

        // P = exp2(S*coef) with causal mask; no max subtraction (bounded)
        const bool diag = (jt == n - 1);
#pragma unroll
        for (int js = 0; js < 4; ++js) {
            const int jj = j0 + js * 16 + l16;
            const int cb = js * 2 + (l16 >> 3);
            const int e  = l16 & 7;
#pragma unroll
            for (int r = 0; r < 4; ++r) {
                float vv = S[js][r] * coef;
                if (diag && (jj > qt * 16 + quad * 4 + r)) vv = -INFINITY;
                float p = exp2f(vv);             // exp2(-inf) = 0
                lp[r] += p;
                const int i = quad * 4 + r;
                psw[(i * 8 + (cb ^ (i & 7))) * 8 + e] = f2bf(p);
            }
        }

        // O += P V  (A-frags from swizzled LDS, B-frags already in registers)
#pragma unroll
        for (int jc = 0; jc < 2; ++jc) {
            const int pblk = l16 * 8 + ((jc * 4 + quad) ^ (l16 & 7));
            bf16x8 pa = *(const bf16x8*)&psw[pblk * 8];
#pragma unroll
            for (int f = 0; f < 8; ++f)
                O[f] = __builtin_amdgcn_mfma_f32_16x16x32_bf16(pa, vfr[jc * 8 + f], O[f], 0, 0, 0);
        }
    }

    // ---- l: reduce across the row's 16 lanes, stash per wave ----
#pragma unroll
    for (int r = 0; r < 4; ++r) {
        float s = lp[r];
        s += __shfl_xor(s, 1);
        s += __shfl_xor(s, 2);
        s += __shfl_xor(s, 4);
        s += __shfl_xor(s, 8);
        lp[r] = s;
    }
    if (l16 == 0) {
#pragma unroll
        for (int r = 0; r < 4; ++r) lbuf[wave][quad * 4 + r] = lp[r];
    }
    __syncthreads();   // obuf zeroing + lbuf visible; all waves done with loop

    // merge O partials (addition-only: no-max softmax makes partials additive)
#pragma unroll
    for (int f = 0; f < 8; ++f)
#pragma unroll
        for (int r = 0; r < 4; ++r)
            atomicAdd(&obuf[quad * 4 + r][f * 16 + l16], O[f][r]);
    __syncthreads();

    {   // final: 16 rows x 128 cols = 2048 outs / 256 thr
        const int row = tid >> 4;
        const int c8  = (tid & 15) * 8;
        float L = lbuf[0][row] + lbuf[1][row] + lbuf[2][row] + lbuf[3][row];
        const float inv = 1.f / L;
        float* dst = out + (size_t)(b * SEQ + qt * 16 + row) * HD + c8;
#pragma unroll
        for (int u = 0; u < 8; ++u) dst[u] = obuf[row][c8 + u] * inv;
    }
}

extern "C" void kernel_launch(void* const* d_in, const int* in_sizes, int n_in,
                              void* d_out, int out_size, void* d_ws, size_t ws_size,
                              hipStream_t stream) {
    const float* x  = (const float*)d_in[0];
    const float* Wk = (const float*)d_in[1];
    // d_in[2] = Wq is UNUSED: reference uses the key projection for q (source bug)
    const float* Wv = (const float*)d_in[3];
    float* out = (float*)d_out;

    short* Wp   = (short*)d_ws;                          // 512 KB
    short* Kbuf = Wp + (size_t)256 * 1024;               // [B*T, H] bf16, 4 MB
    short* Vt   = Kbuf + (size_t)BATCH * SEQ * HD;       // [B, H, T] bf16, 4 MB

    prep_w<<<128, 256, 0, stream>>>(Wk, Wv, Wp);
    proj_kernel<<<512, 256, 0, stream>>>(x, Wp, Kbuf, Vt);
    attn_kernel<<<1024, 256, 0, stream>>>(Kbuf, Vt, out);
}

// Round 6
// 164.474 us; speedup vs baseline: 1.5872x; 1.5872x over previous
//
#include <hip/hip_runtime.h>
#include <hip/hip_bf16.h>

// Problem constants (B,T,C,H from reference)
#define BATCH 8
#define SEQ   2048
#define EMB   1024
#define HD    128

typedef __attribute__((ext_vector_type(8))) short bf16x8;  // MFMA A/B frag (4 VGPR)
typedef __attribute__((ext_vector_type(4))) short bf16x4;
typedef __attribute__((ext_vector_type(4))) float f32x4;   // MFMA C/D frag

__device__ __forceinline__ short f2bf(float f) {           // RNE
    union { float f; unsigned u; } v; v.f = f;
    unsigned r = v.u + 0x7fffu + ((v.u >> 16) & 1u);
    return (short)(r >> 16);
}

// ===========================================================================
// FRAGMENT-IMAGE LAYOUTS (the whole point of v6):
// every MFMA B/A fragment is ONE contiguous 1KB region = one fully-coalesced
// 16B/lane load for the consuming wave. Previous rounds' frag loads spanned
// 16 rows x 256B stride = 4-8x L2 over-traffic; that was the real gate.
//
// W image (per nh half 0=K,1=V; per k-chunk kc of 64):  16KB
//   slot(kk,f,l,q) = ((kk*8+f)*16+l)*4+q   (8 shorts each)
//   holds W[n = nh*128+f*16+l][k = kc*64+kk*32+q*8+e]
// K image (per b, per 64-row tile jt): 16KB
//   slot(kc,js,l,q) = ((kc*4+js)*16+l)*4+q
//   holds K[j = js*16+l][h = kc*32+q*8+e]         (j local to tile)
// V image (per b, jt): 16KB
//   slot(jc,f,l,q) = ((jc*8+f)*16+l)*4+q
//   holds V[j = jc*32+q*8+e][h = f*16+l]
// ===========================================================================

// ---------------------------------------------------------------------------
// prep_w: fp32 Wk/Wv -> bf16 W-fragment images. 32768 threads, coalesced out.
// ---------------------------------------------------------------------------
__global__ void prep_w(const float* __restrict__ Wk, const float* __restrict__ Wv,
                       short* __restrict__ Wimg) {
    int g  = blockIdx.x * 256 + threadIdx.x;   // 0..32767
    int q  = g & 3;
    int l  = (g >> 2) & 15;
    int f  = (g >> 6) & 7;
    int kk = (g >> 9) & 1;
    int kc = (g >> 10) & 15;
    int nh = (g >> 14) & 1;
    const float* src = (nh ? Wv : Wk) + (size_t)(f * 16 + l) * EMB + kc * 64 + kk * 32 + q * 8;
    float4 f0 = *(const float4*)src;
    float4 f1 = *(const float4*)(src + 4);
    bf16x8 v;
    v[0]=f2bf(f0.x); v[1]=f2bf(f0.y); v[2]=f2bf(f0.z); v[3]=f2bf(f0.w);
    v[4]=f2bf(f1.x); v[5]=f2bf(f1.y); v[6]=f2bf(f1.z); v[7]=f2bf(f1.w);
    *(bf16x8*)&Wimg[(size_t)g * 8] = v;
}

// ---------------------------------------------------------------------------
// proj_kernel v6 (m97-style): [K|V] = x @ [Wk|Wv]^T -> K/V fragment images.
// Grid 512 x 256thr: bx -> nh = bx&1 (K or V half), mt = bx>>1 (64-row tile).
// Per k-chunk (64): x staged to LDS A-image (coalesced fp32 read + one cvt),
// W-image identity-copied to LDS; double-buffered, ONE barrier per chunk.
// Waves split the N dim (32 cols each): 12KB ds_read + 16 MFMA /wave/chunk.
// Epilogue: C scattered into the output image in LDS, then contiguous copy.
// ---------------------------------------------------------------------------
__global__ __launch_bounds__(256, 2)
void proj_kernel(const float* __restrict__ x, const short* __restrict__ Wimg,
                 short* __restrict__ Kimg,    // [8][32] 16KB images
                 short* __restrict__ Vimg)    // [8][32] 16KB images
{
    __shared__ __align__(16) union {
        struct { short A[2][4096]; short B[2][8192]; } st;  // 16KB + 32KB dbuf
        short ep[8192];                                     // 16KB epilogue image
    } sm;

    const int tid  = threadIdx.x;
    const int wave = tid >> 6;       // = n-quarter (32 cols)
    const int lane = tid & 63;
    const int quad = lane >> 4;
    const int l16  = lane & 15;
    const int nh   = blockIdx.x & 1;
    const int mt   = blockIdx.x >> 1;      // 0..255
    const int row0 = mt * 64;

    // x staging coords: thread t = (row m, 16-float seg)
    const int m_st  = tid >> 2;
    const int seg   = tid & 3;
    const int mf_st = m_st >> 4, l_st = m_st & 15;
    const float* xsrc = x + (size_t)(row0 + m_st) * EMB + seg * 16;
    const short* wsrc = Wimg + (size_t)nh * 131072;   // + kc*8192

    f32x4 acc[4][2];                 // [mf][f2]: rows mf*16+quad*4+r, col w*32+f2*16+l16
#pragma unroll
    for (int a = 0; a < 4; ++a)
#pragma unroll
        for (int c = 0; c < 2; ++c) acc[a][c] = f32x4{0.f, 0.f, 0.f, 0.f};

    // ---- prime chunk 0 into buffer 0 ----
    {
        float4 xv[4];
#pragma unroll
        for (int e = 0; e < 4; ++e) xv[e] = *(const float4*)(xsrc + e * 4);
#pragma unroll
        for (int i = 0; i < 4; ++i)
            *(bf16x8*)&sm.st.B[0][tid * 32 + i * 8] = *(const bf16x8*)&wsrc[tid * 32 + i * 8];
#pragma unroll
        for (int e = 0; e < 4; ++e) {
            int k_in = seg * 16 + e * 4;
            int kk = k_in >> 5, q = (k_in >> 3) & 3, hh = (k_in >> 2) & 1;
            bf16x4 h4 = { f2bf(xv[e].x), f2bf(xv[e].y), f2bf(xv[e].z), f2bf(xv[e].w) };
            *(bf16x4*)&sm.st.A[0][((((mf_st * 2 + kk) * 16 + l_st) * 4 + q) * 8) + hh * 4] = h4;
        }
    }
    __syncthreads();

    for (int kc = 0; kc < 16; ++kc) {
        const int cur = kc & 1, nxt = cur ^ 1;
        float4 xv[4];
        bf16x8 wl[4];
        if (kc < 15) {               // issue next chunk's global loads first
            const float* nx = xsrc + (kc + 1) * 64;
#pragma unroll
            for (int e = 0; e < 4; ++e) xv[e] = *(const float4*)(nx + e * 4);
            const short* nw = wsrc + (size_t)(kc + 1) * 8192;
#pragma unroll
            for (int i = 0; i < 4; ++i) wl[i] = *(const bf16x8*)&nw[tid * 32 + i * 8];
        }

        // compute chunk kc: A-frags (mf,kk), B-frags (f2,kk), 16 MFMA
#pragma unroll
        for (int kk = 0; kk < 2; ++kk) {
            bf16x8 bfr[2];
#pragma unroll
            for (int f2 = 0; f2 < 2; ++f2)
                bfr[f2] = *(const bf16x8*)&sm.st.B[cur][(((kk * 8 + wave * 2 + f2) * 16 + l16) * 4 + quad) * 8];
#pragma unroll
            for (int mf = 0; mf < 4; ++mf) {
                bf16x8 af = *(const bf16x8*)&sm.st.A[cur][(((mf * 2 + kk) * 16 + l16) * 4 + quad) * 8];
#pragma unroll
                for (int f2 = 0; f2 < 2; ++f2)
                    acc[mf][f2] = __builtin_amdgcn_mfma_f32_16x16x32_bf16(af, bfr[f2], acc[mf][f2], 0, 0, 0);
            }
        }

        if (kc < 15) {               // stage next chunk
#pragma unroll
            for (int i = 0; i < 4; ++i)
                *(bf16x8*)&sm.st.B[nxt][tid * 32 + i * 8] = wl[i];
#pragma unroll
            for (int e = 0; e < 4; ++e) {
                int k_in = seg * 16 + e * 4;
                int kk = k_in >> 5, q = (k_in >> 3) & 3, hh = (k_in >> 2) & 1;
                bf16x4 h4 = { f2bf(xv[e].x), f2bf(xv[e].y), f2bf(xv[e].z), f2bf(xv[e].w) };
                *(bf16x4*)&sm.st.A[nxt][((((mf_st * 2 + kk) * 16 + l_st) * 4 + q) * 8) + hh * 4] = h4;
            }
        }
        __syncthreads();
    }

    // ---- epilogue: scatter C into the output fragment image in LDS ----
    // (all waves are past their last st reads: safe to reuse the union)
#pragma unroll
    for (int mf = 0; mf < 4; ++mf)
#pragma unroll
        for (int f2 = 0; f2 < 2; ++f2)
#pragma unroll
            for (int r = 0; r < 4; ++r) {
                const int row = mf * 16 + quad * 4 + r;         // j within 64-tile
                const int h   = wave * 32 + f2 * 16 + l16;      // output col 0..127
                int idx;
                if (nh == 0)   // K image: slot(kc,js,l,q)+e from (row->js,l ; h->kc,q,e)
                    idx = ((((h >> 5) * 4 + (row >> 4)) * 16 + (row & 15)) * 4 + ((h >> 3) & 3)) * 8 + (h & 7);
                else           // V image: slot(jc,f,l,q)+e from (h->f,l ; row->jc,q,e)
                    idx = ((((row >> 5) * 8 + (h >> 4)) * 16 + (h & 15)) * 4 + ((row >> 3) & 3)) * 8 + (row & 7);
                sm.ep[idx] = f2bf(acc[mf][f2][r]);
            }
    __syncthreads();

    {   // contiguous 16KB image copy to global
        short* dst = (nh == 0 ? Kimg : Vimg) + (size_t)mt * 8192 + tid * 32;
#pragma unroll
        for (int i = 0; i < 4; ++i)
            *(bf16x8*)(dst + i * 8) = *(const bf16x8*)&sm.ep[tid * 32 + i * 8];
    }
}

// ---------------------------------------------------------------------------
// attn_kernel v6: causal flash attention, q == k (reference bug).
// K/V consumed from fragment images: every frag = one contiguous 1KB load.
// Grid 512 x 128thr: b = bx&7 (XCD swizzle); each of the 2 waves owns ONE
// 16-row q-tile (qtu = (bx>>3)*2 + wave, long/short paired per block for CU
// balance). No cross-wave merge, no block barriers. No-max softmax (bounded
// scores), lane-local l partials, per-wave swizzled P bridge (R4/5-verified).
// ---------------------------------------------------------------------------
#define LOG2E 1.4426950408889634f

__global__ __launch_bounds__(128, 1)
void attn_kernel(const short* __restrict__ Kimg,  // [8][32] images
                 const short* __restrict__ Vimg,  // [8][32] images
                 float* __restrict__ out)         // [B, T, H] fp32
{
    __shared__ __align__(16) short ps[2][1024];   // per-wave swizzled P (16x64)

    const int tid  = threadIdx.x;
    const int wave = tid >> 6;
    const int lane = tid & 63;
    const int quad = lane >> 4;
    const int l16  = lane & 15;

    const int b   = blockIdx.x & 7;                       // XCD-affinity
    const int qtu = (blockIdx.x >> 3) * 2 + wave;         // 0..127
    const int qt  = (qtu & 1) ? (127 - (qtu >> 1)) : (qtu >> 1);  // balance pair
    const int n   = (qt >> 2) + 1;                        // 64-wide j-tiles

    const short* Kb = Kimg + (size_t)b * 32 * 8192;
    const short* Vb = Vimg + (size_t)b * 32 * 8192;

    // Q fragments from the diagonal K-image (Q = K projection)
    bf16x8 qf[4];
    {
        const short* qi = Kb + (size_t)(qt >> 2) * 8192;
        const int jsq = qt & 3;
#pragma unroll
        for (int kc = 0; kc < 4; ++kc)
            qf[kc] = *(const bf16x8*)&qi[(((kc * 4 + jsq) * 16 + l16) * 4 + quad) * 8];
    }

    f32x4 O[8];
#pragma unroll
    for (int f = 0; f < 8; ++f) O[f] = f32x4{0.f, 0.f, 0.f, 0.f};
    float lp[4] = {0.f, 0.f, 0.f, 0.f};

    const float coef = LOG2E * 0.03125f;   // log2(e)/sqrt(C), sqrt(1024)=32
    short* psw = ps[wave];

    for (int jt = 0; jt < n; ++jt) {
        const short* ki = Kb + (size_t)jt * 8192;
        const short* vi = Vb + (size_t)jt * 8192;

        // 16 contiguous K-frag loads, then S MFMAs
        bf16x8 kfr[16];
#pragma unroll
        for (int kc = 0; kc < 4; ++kc)
#pragma unroll
            for (int js = 0; js < 4; ++js)
                kfr[kc * 4 + js] = *(const bf16x8*)&ki[(((kc * 4 + js) * 16 + l16) * 4 + quad) * 8];

        f32x4 S[4];
#pragma unroll
        for (int js = 0; js < 4; ++js) S[js] = f32x4{0.f, 0.f, 0.f, 0.f};
#pragma unroll
        for (int kc = 0; kc < 4; ++kc)
#pragma unroll
            for (int js = 0; js < 4; ++js)
                S[js] = __builtin_amdgcn_mfma_f32_16x16x32_bf16(qf[kc], kfr[kc * 4 + js], S[js], 0, 0, 0);

        // V-frag loads fly during exp + P round-trip
        bf16x8 vfr[16];
#pragma unroll
        for (int jc = 0; jc < 2; ++jc)
#pragma unroll
            for (int f = 0; f < 8; ++f)
                vfr[jc * 8 + f] = *(const bf16x8*)&vi[(((jc * 8 + f) * 16 + l16) * 4 + quad) * 8];

        // P = exp2(S*coef) with causal mask (no max: scores bounded, fp32-safe)
        const bool diag = (jt == n - 1);
#pragma unroll
        for (int js = 0; js < 4; ++js) {
            const int jj = jt * 64 + js * 16 + l16;
            const int cb = js * 2 + (l16 >> 3);
            const int e  = l16 & 7;
#pragma unroll
            for (int r = 0; r < 4; ++r) {
                float vv = S[js][r] * coef;
                if (diag && (jj > qt * 16 + quad * 4 + r)) vv = -INFINITY;
                float p = exp2f(vv);             // exp2(-inf) = 0
                lp[r] += p;
                const int i8 = quad * 4 + r;
                psw[(i8 * 8 + (cb ^ (i8 & 7))) * 8 + e] = f2bf(p);
            }
        }

        // O += P V  (A from swizzled LDS, B already in registers)
#pragma unroll
        for (int jc = 0; jc < 2; ++jc) {
            const int pblk = l16 * 8 + ((jc * 4 + quad) ^ (l16 & 7));
            bf16x8 pa = *(const bf16x8*)&psw[pblk * 8];
#pragma unroll
            for (int f = 0; f < 8; ++f)
                O[f] = __builtin_amdgcn_mfma_f32_16x16x32_bf16(pa, vfr[jc * 8 + f], O[f], 0, 0, 0);
        }
    }

    // ---- l reduce across the row's 16 lanes; direct stores (no merge) ----
#pragma unroll
    for (int r = 0; r < 4; ++r) {
        float s = lp[r];
        s += __shfl_xor(s, 1);
        s += __shfl_xor(s, 2);
        s += __shfl_xor(s, 4);
        s += __shfl_xor(s, 8);
        lp[r] = s;
    }
#pragma unroll
    for (int r = 0; r < 4; ++r) {
        const float inv = 1.f / lp[r];
        const int row = qt * 16 + quad * 4 + r;
        float* dst = out + (size_t)(b * SEQ + row) * HD + l16;
#pragma unroll
        for (int f = 0; f < 8; ++f)
            dst[f * 16] = O[f][r] * inv;
    }
}

extern "C" void kernel_launch(void* const* d_in, const int* in_sizes, int n_in,
                              void* d_out, int out_size, void* d_ws, size_t ws_size,
                              hipStream_t stream) {
    const float* x  = (const float*)d_in[0];
    const float* Wk = (const float*)d_in[1];
    // d_in[2] = Wq is UNUSED: reference uses the key projection for q (source bug)
    const float* Wv = (const float*)d_in[3];
    float* out = (float*)d_out;

    short* Wimg = (short*)d_ws;                          // 2*16 images  = 512 KB
    short* Kimg = Wimg + (size_t)262144;                 // 8*32 images  = 4 MB
    short* Vimg = Kimg + (size_t)BATCH * 32 * 8192;      // 8*32 images  = 4 MB

    prep_w<<<128, 256, 0, stream>>>(Wk, Wv, Wimg);
    proj_kernel<<<512, 256, 0, stream>>>(x, Wimg, Kimg, Vimg);
    attn_kernel<<<512, 128, 0, stream>>>(Kimg, Vimg, out);
}

// Round 7
// 158.017 us; speedup vs baseline: 1.6520x; 1.0409x over previous
//
#include <hip/hip_runtime.h>
#include <hip/hip_bf16.h>

// Problem constants (B,T,C,H from reference)
#define BATCH 8
#define SEQ   2048
#define EMB   1024
#define HD    128

typedef __attribute__((ext_vector_type(8))) short bf16x8;  // MFMA A/B frag (4 VGPR)
typedef __attribute__((ext_vector_type(4))) float f32x4;   // MFMA C/D frag

__device__ __forceinline__ short f2bf(float f) {           // RNE
    union { float f; unsigned u; } v; v.f = f;
    unsigned r = v.u + 0x7fffu + ((v.u >> 16) & 1u);
    return (short)(r >> 16);
}

// ===========================================================================
// FRAGMENT-IMAGE LAYOUTS (R6-verified): every MFMA fragment = one contiguous
// 1KB region = one fully-coalesced 16B/lane load for the consuming wave.
// W image (nh 0=K,1=V; k-chunk kc): slot(kk,f,l,q) -> W[nh*128+f*16+l][kc*64+kk*32+q*8+e]
// K image (b, jt): slot(kc,js,l,q) -> K[js*16+l][kc*32+q*8+e]
// V image (b, jt): slot(jc,f,l,q)  -> V[jc*32+q*8+e][f*16+l]
// ===========================================================================

__global__ void prep_w(const float* __restrict__ Wk, const float* __restrict__ Wv,
                       short* __restrict__ Wimg) {
    int g  = blockIdx.x * 256 + threadIdx.x;   // 0..32767
    int q  = g & 3;
    int l  = (g >> 2) & 15;
    int f  = (g >> 6) & 7;
    int kk = (g >> 9) & 1;
    int kc = (g >> 10) & 15;
    int nh = (g >> 14) & 1;
    const float* src = (nh ? Wv : Wk) + (size_t)(f * 16 + l) * EMB + kc * 64 + kk * 32 + q * 8;
    float4 f0 = *(const float4*)src;
    float4 f1 = *(const float4*)(src + 4);
    bf16x8 v;
    v[0]=f2bf(f0.x); v[1]=f2bf(f0.y); v[2]=f2bf(f0.z); v[3]=f2bf(f0.w);
    v[4]=f2bf(f1.x); v[5]=f2bf(f1.y); v[6]=f2bf(f1.z); v[7]=f2bf(f1.w);
    *(bf16x8*)&Wimg[(size_t)g * 8] = v;
}

// ---------------------------------------------------------------------------
// proj_kernel v7: [K|V] = x @ [Wk|Wv]^T -> K/V fragment images.
// vs R6: A staged in NATURAL PADDED ROWS (contiguous b128 writes, 2-way-free
// b128 reads) instead of the scattered A-image (R6's 5.9M bank conflicts).
// W-image identity-copied to LDS (contiguous both ways). Double-buffered,
// one barrier/chunk. 4 waves split N (32 cols each). LDS ~50KB -> 3 blk/CU.
// ---------------------------------------------------------------------------
__global__ __launch_bounds__(256, 2)
void proj_kernel(const float* __restrict__ x, const short* __restrict__ Wimg,
                 short* __restrict__ Kimg,    // [8][32] 16KB images
                 short* __restrict__ Vimg)    // [8][32] 16KB images
{
    __shared__ __align__(16) union {
        struct { short A[2][64][72]; short B[2][8192]; } st;  // 18.4 + 32 KB
        short ep[8192];                                       // 16KB epilogue
    } sm;

    const int tid  = threadIdx.x;
    const int wave = tid >> 6;       // n-quarter (32 cols)
    const int lane = tid & 63;
    const int quad = lane >> 4;
    const int l16  = lane & 15;
    const int nh   = blockIdx.x & 1;
    const int mt   = blockIdx.x >> 1;      // 0..255
    const int row0 = mt * 64;

    // x staging: thread t = (row t>>2, 16-float seg t&3) -> 64B/lane coalesced
    const int srow = tid >> 2;
    const int sseg = tid & 3;
    const float* xsrc = x + (size_t)(row0 + srow) * EMB + sseg * 16;
    const short* wsrc = Wimg + (size_t)nh * 131072;   // + kc*8192

    f32x4 acc[4][2];                 // [mf][f2]
#pragma unroll
    for (int a = 0; a < 4; ++a)
#pragma unroll
        for (int c = 0; c < 2; ++c) acc[a][c] = f32x4{0.f, 0.f, 0.f, 0.f};

    // ---- prime chunk 0 ----
    {
        float4 xv[4];
#pragma unroll
        for (int e = 0; e < 4; ++e) xv[e] = *(const float4*)(xsrc + e * 4);
#pragma unroll
        for (int i = 0; i < 4; ++i)
            *(bf16x8*)&sm.st.B[0][tid * 32 + i * 8] = *(const bf16x8*)&wsrc[tid * 32 + i * 8];
        bf16x8 v0, v1;
        v0[0]=f2bf(xv[0].x); v0[1]=f2bf(xv[0].y); v0[2]=f2bf(xv[0].z); v0[3]=f2bf(xv[0].w);
        v0[4]=f2bf(xv[1].x); v0[5]=f2bf(xv[1].y); v0[6]=f2bf(xv[1].z); v0[7]=f2bf(xv[1].w);
        v1[0]=f2bf(xv[2].x); v1[1]=f2bf(xv[2].y); v1[2]=f2bf(xv[2].z); v1[3]=f2bf(xv[2].w);
        v1[4]=f2bf(xv[3].x); v1[5]=f2bf(xv[3].y); v1[6]=f2bf(xv[3].z); v1[7]=f2bf(xv[3].w);
        *(bf16x8*)&sm.st.A[0][srow][sseg * 16]     = v0;
        *(bf16x8*)&sm.st.A[0][srow][sseg * 16 + 8] = v1;
    }
    __syncthreads();

    for (int kc = 0; kc < 16; ++kc) {
        const int cur = kc & 1, nxt = cur ^ 1;
        float4 xv[4];
        bf16x8 wl[4];
        if (kc < 15) {               // next chunk's global loads fly first
            const float* nx = xsrc + (kc + 1) * 64;
#pragma unroll
            for (int e = 0; e < 4; ++e) xv[e] = *(const float4*)(nx + e * 4);
            const short* nw = wsrc + (size_t)(kc + 1) * 8192;
#pragma unroll
            for (int i = 0; i < 4; ++i) wl[i] = *(const bf16x8*)&nw[tid * 32 + i * 8];
        }

        // compute chunk kc
#pragma unroll
        for (int kk = 0; kk < 2; ++kk) {
            bf16x8 bfr[2];
#pragma unroll
            for (int f2 = 0; f2 < 2; ++f2)
                bfr[f2] = *(const bf16x8*)&sm.st.B[cur][(((kk * 8 + wave * 2 + f2) * 16 + l16) * 4 + quad) * 8];
#pragma unroll
            for (int mf = 0; mf < 4; ++mf) {
                bf16x8 af = *(const bf16x8*)&sm.st.A[cur][mf * 16 + l16][kk * 32 + quad * 8];
#pragma unroll
                for (int f2 = 0; f2 < 2; ++f2)
                    acc[mf][f2] = __builtin_amdgcn_mfma_f32_16x16x32_bf16(af, bfr[f2], acc[mf][f2], 0, 0, 0);
            }
        }

        if (kc < 15) {               // stage next chunk
#pragma unroll
            for (int i = 0; i < 4; ++i)
                *(bf16x8*)&sm.st.B[nxt][tid * 32 + i * 8] = wl[i];
            bf16x8 v0, v1;
            v0[0]=f2bf(xv[0].x); v0[1]=f2bf(xv[0].y); v0[2]=f2bf(xv[0].z); v0[3]=f2bf(xv[0].w);
            v0[4]=f2bf(xv[1].x); v0[5]=f2bf(xv[1].y); v0[6]=f2bf(xv[1].z); v0[7]=f2bf(xv[1].w);
            v1[0]=f2bf(xv[2].x); v1[1]=f2bf(xv[2].y); v1[2]=f2bf(xv[2].z); v1[3]=f2bf(xv[2].w);
            v1[4]=f2bf(xv[3].x); v1[5]=f2bf(xv[3].y); v1[6]=f2bf(xv[3].z); v1[7]=f2bf(xv[3].w);
            *(bf16x8*)&sm.st.A[nxt][srow][sseg * 16]     = v0;
            *(bf16x8*)&sm.st.A[nxt][srow][sseg * 16 + 8] = v1;
        }
        __syncthreads();
    }

    // ---- epilogue: scatter C into the output fragment image in LDS ----
#pragma unroll
    for (int mf = 0; mf < 4; ++mf)
#pragma unroll
        for (int f2 = 0; f2 < 2; ++f2)
#pragma unroll
            for (int r = 0; r < 4; ++r) {
                const int row = mf * 16 + quad * 4 + r;         // j within 64-tile
                const int h   = wave * 32 + f2 * 16 + l16;      // output col 0..127
                int idx;
                if (nh == 0)
                    idx = ((((h >> 5) * 4 + (row >> 4)) * 16 + (row & 15)) * 4 + ((h >> 3) & 3)) * 8 + (h & 7);
                else
                    idx = ((((row >> 5) * 8 + (h >> 4)) * 16 + (h & 15)) * 4 + ((row >> 3) & 3)) * 8 + (row & 7);
                sm.ep[idx] = f2bf(acc[mf][f2][r]);
            }
    __syncthreads();

    {   // contiguous 16KB image copy to global
        short* dst = (nh == 0 ? Kimg : Vimg) + (size_t)mt * 8192 + tid * 32;
#pragma unroll
        for (int i = 0; i < 4; ++i)
            *(bf16x8*)(dst + i * 8) = *(const bf16x8*)&sm.ep[tid * 32 + i * 8];
    }
}

// ---------------------------------------------------------------------------
// attn_kernel v7: causal flash attention, q == k (reference bug).
// vs R6: each q-tile's j-range is SPLIT ACROSS 2 WAVES (even/odd jt) ->
// 2048 wave-tasks = 2+ waves/SIMD (R6 had exactly 1: zero latency overlap).
// No-max softmax partials are ADDITIVE: wave p=1 dumps (O,l) to LDS, wave
// p=0 adds and stores. Block = 4 waves = 2 paired q-tiles (g, 127-g).
// K/V from fragment images: every frag load = contiguous 1KB/wave.
// ---------------------------------------------------------------------------
#define LOG2E 1.4426950408889634f

__global__ __launch_bounds__(256, 2)
void attn_kernel(const short* __restrict__ Kimg,  // [8][32] images
                 const short* __restrict__ Vimg,  // [8][32] images
                 float* __restrict__ out)         // [B, T, H] fp32
{
    __shared__ __align__(16) short ps[4][1024];   // per-wave swizzled P (16x64)
    __shared__ float obuf[2][16][132];            // p=1 partial O (+4 pad)
    __shared__ float lbuf[2][16];                 // p=1 partial l

    const int tid  = threadIdx.x;
    const int wave = tid >> 6;
    const int lane = tid & 63;
    const int quad = lane >> 4;
    const int l16  = lane & 15;

    const int b    = blockIdx.x & 7;              // XCD-affinity
    const int g    = blockIdx.x >> 3;             // 0..63
    const int pair = wave >> 1;                   // 0 -> qt=g, 1 -> qt=127-g
    const int p    = wave & 1;                    // j-parity of this wave
    const int qt   = pair ? (127 - g) : g;
    const int n    = (qt >> 2) + 1;               // 64-wide j-tiles (causal)

    const short* Kb = Kimg + (size_t)b * 32 * 8192;
    const short* Vb = Vimg + (size_t)b * 32 * 8192;

    // Q fragments from the diagonal K-image (Q = K projection)
    bf16x8 qf[4];
    {
        const short* qi = Kb + (size_t)(qt >> 2) * 8192;
        const int jsq = qt & 3;
#pragma unroll
        for (int kc = 0; kc < 4; ++kc)
            qf[kc] = *(const bf16x8*)&qi[(((kc * 4 + jsq) * 16 + l16) * 4 + quad) * 8];
    }

    f32x4 O[8];
#pragma unroll
    for (int f = 0; f < 8; ++f) O[f] = f32x4{0.f, 0.f, 0.f, 0.f};
    float lp[4] = {0.f, 0.f, 0.f, 0.f};

    const float coef = LOG2E * 0.03125f;   // log2(e)/sqrt(C), sqrt(1024)=32
    short* psw = ps[wave];

    for (int jt = p; jt < n; jt += 2) {
        const short* ki = Kb + (size_t)jt * 8192;
        const short* vi = Vb + (size_t)jt * 8192;

        // 16 contiguous K-frag loads, then S MFMAs
        bf16x8 kfr[16];
#pragma unroll
        for (int kc = 0; kc < 4; ++kc)
#pragma unroll
            for (int js = 0; js < 4; ++js)
                kfr[kc * 4 + js] = *(const bf16x8*)&ki[(((kc * 4 + js) * 16 + l16) * 4 + quad) * 8];

        f32x4 S[4];
#pragma unroll
        for (int js = 0; js < 4; ++js) S[js] = f32x4{0.f, 0.f, 0.f, 0.f};
#pragma unroll
        for (int kc = 0; kc < 4; ++kc)
#pragma unroll
            for (int js = 0; js < 4; ++js)
                S[js] = __builtin_amdgcn_mfma_f32_16x16x32_bf16(qf[kc], kfr[kc * 4 + js], S[js], 0, 0, 0);

        // V-frag loads fly during exp + P round-trip
        bf16x8 vfr[16];
#pragma unroll
        for (int jc = 0; jc < 2; ++jc)
#pragma unroll
            for (int f = 0; f < 8; ++f)
                vfr[jc * 8 + f] = *(const bf16x8*)&vi[(((jc * 8 + f) * 16 + l16) * 4 + quad) * 8];

        // P = exp2(S*coef) with causal mask (no max: scores bounded, fp32-safe)
        const bool diag = (jt == n - 1);
#pragma unroll
        for (int js = 0; js < 4; ++js) {
            const int jj = jt * 64 + js * 16 + l16;
            const int cb = js * 2 + (l16 >> 3);
            const int e  = l16 & 7;
#pragma unroll
            for (int r = 0; r < 4; ++r) {
                float vv = S[js][r] * coef;
                if (diag && (jj > qt * 16 + quad * 4 + r)) vv = -INFINITY;
                float pe = exp2f(vv);            // exp2(-inf) = 0
                lp[r] += pe;
                const int i8 = quad * 4 + r;
                psw[(i8 * 8 + (cb ^ (i8 & 7))) * 8 + e] = f2bf(pe);
            }
        }

        // O += P V  (A from swizzled LDS, B already in registers)
#pragma unroll
        for (int jc = 0; jc < 2; ++jc) {
            const int pblk = l16 * 8 + ((jc * 4 + quad) ^ (l16 & 7));
            bf16x8 pa = *(const bf16x8*)&psw[pblk * 8];
#pragma unroll
            for (int f = 0; f < 8; ++f)
                O[f] = __builtin_amdgcn_mfma_f32_16x16x32_bf16(pa, vfr[jc * 8 + f], O[f], 0, 0, 0);
        }
    }

    // ---- l: reduce across the row's 16 lanes ----
#pragma unroll
    for (int r = 0; r < 4; ++r) {
        float s = lp[r];
        s += __shfl_xor(s, 1);
        s += __shfl_xor(s, 2);
        s += __shfl_xor(s, 4);
        s += __shfl_xor(s, 8);
        lp[r] = s;
    }

    // ---- additive merge: p=1 dumps partials, p=0 adds and stores ----
    if (p == 1) {
#pragma unroll
        for (int f = 0; f < 8; ++f)
#pragma unroll
            for (int r = 0; r < 4; ++r)
                obuf[pair][quad * 4 + r][f * 16 + l16] = O[f][r];
        if (l16 == 0) {
#pragma unroll
            for (int r = 0; r < 4; ++r) lbuf[pair][quad * 4 + r] = lp[r];
        }
    }
    __syncthreads();

    if (p == 0) {
#pragma unroll
        for (int r = 0; r < 4; ++r) {
            const int row16 = quad * 4 + r;
            const float L   = lp[r] + lbuf[pair][row16];
            const float inv = 1.f / L;
            const int row   = qt * 16 + row16;
            float* dst = out + (size_t)(b * SEQ + row) * HD + l16;
#pragma unroll
            for (int f = 0; f < 8; ++f)
                dst[f * 16] = (O[f][r] + obuf[pair][row16][f * 16 + l16]) * inv;
        }
    }
}

extern "C" void kernel_launch(void* const* d_in, const int* in_sizes, int n_in,
                              void* d_out, int out_size, void* d_ws, size_t ws_size,
                              hipStream_t stream) {
    const float* x  = (const float*)d_in[0];
    const float* Wk = (const float*)d_in[1];
    // d_in[2] = Wq is UNUSED: reference uses the key projection for q (source bug)
    const float* Wv = (const float*)d_in[3];
    float* out = (float*)d_out;

    short* Wimg = (short*)d_ws;                          // 512 KB
    short* Kimg = Wimg + (size_t)262144;                 // 4 MB
    short* Vimg = Kimg + (size_t)BATCH * 32 * 8192;      // 4 MB

    prep_w<<<128, 256, 0, stream>>>(Wk, Wv, Wimg);
    proj_kernel<<<512, 256, 0, stream>>>(x, Wimg, Kimg, Vimg);
    attn_kernel<<<512, 256, 0, stream>>>(Kimg, Vimg, out);
}